// Round 2
// baseline (375.423 us; speedup 1.0000x reference)
//
#include <hip/hip_runtime.h>
#include <math.h>

typedef _Float16 half_t;
typedef __attribute__((ext_vector_type(8))) _Float16 half8;
typedef __attribute__((ext_vector_type(4))) _Float16 half4;
typedef __attribute__((ext_vector_type(4))) float floatx4;

#define TDIM 36
#define PDIM 161        // 2*80+1 atoms
#define NCOL 50
#define DHALF 25        // columns per block (d split across 2 blocks per batch)
#define NITER 100
#define PITER2 200      // power steps on G^2 == 400 on G (proven accuracy)

// GEMM geometry per block: phase A M=48,N=32,K=192 ; phase B M=176,N=32,K=64
#define NKA 6
#define NKB 2
#define YKS 192         // Y row stride (halves) = 384 B; bank-aligned + XOR swizzle
#define RKS 64          // R / Dt row stride (halves) = 128 B; bank-aligned + XOR swizzle
#define SPS 196         // Df (fp32) row stride (dwords)
#define GSTR 44

// XOR swizzle: spread same-column reads across 8 rows -> 8 distinct 16B slots
#define SWZ(row, byteoff) ((byteoff) ^ (((row) & 7) << 4))

// ---- byte-offset LDS map (74,128 B total -> 2 blocks/CU) ----
#define BY_Y    0                      // [32][YKS] half : y^T      (12,288 B)
#define BY_R    12288                  // [32][RKS] half : R^T      ( 4,096 B)
#define BY_GS   16384                  // [36][44] fp32 Gram        ( 6,336 B)
#define BY_G2   22720                  // [36][44] fp32 Gram^2      ( 6,336 B)
#define BY_SC   29056                  // 2 floats: L_inv, thr
#define BY_DTH  29072                  // [176][RKS] half: D^T hi   (22,528 B)
#define BY_DTL  51600                  // [176][RKS] half: D^T lo   (22,528 B)
#define LDS_TOTAL 74128
// setup alias: Df [36][SPS] fp32 = 28,224 B over Y+R+Gs+G2(head).
// Gram dots held in REGISTERS across a barrier so Gs writes don't clobber live Df.
#define MFMA16 __builtin_amdgcn_mfma_f32_16x16x32_f16

__global__ __launch_bounds__(512)
void dan_kernel(const float* __restrict__ xin, const float* __restrict__ rho,
                const float* __restrict__ theta, float* __restrict__ outC,
                float* __restrict__ outDic, float* __restrict__ outR)
{
  extern __shared__ char smc[];
  float*  sc  = (float*)(smc + BY_SC);
  float*  Gs  = (float*)(smc + BY_GS);
  float*  G2  = (float*)(smc + BY_G2);
  float*  Df  = (float*)(smc + BY_Y);   // setup alias

  const int tid = threadIdx.x;
  const int blk = blockIdx.x;
  const int b  = blk >> 1;             // batch item
  const int dh = blk & 1;              // which 25-column half
  const int wave = tid >> 6, lane = tid & 63;
  const int q = lane >> 4, ln = lane & 15;

  // ---- A. zero all LDS (pads must be 0)
  {
    unsigned int* z = (unsigned int*)smc;
    for (int i = tid; i < LDS_TOTAL / 4; i += 512) z[i] = 0u;
  }
  __syncthreads();

  // ---- B. build normalized dictionary (fp32, one column per thread)
  if (tid < PDIM) {
    if (tid == 0) {
      for (int t = 0; t < TDIM; ++t) Df[t * SPS] = 1.0f;
    } else {
      const bool is_sin = tid > 80;
      const int n = is_sin ? (tid - 81) : (tid - 1);
      const float rr = 0.001f + 1.149f / (1.0f + expf(-rho[n]));
      const float th = 3.14159265358979f / (1.0f + expf(-theta[n]));
      const float lr = logf(rr);
      float s2 = 0.0f;
      for (int t = 0; t < TDIM; ++t) {
        const float ft = (float)t;
        const float val = expf(ft * lr) * (is_sin ? sinf(ft * th) : cosf(ft * th));
        Df[t * SPS + tid] = val;
        s2 += val * val;
      }
      const float inv = 1.0f / sqrtf(s2);
      for (int t = 0; t < TDIM; ++t) Df[t * SPS + tid] *= inv;
    }
  }
  __syncthreads();

  // ---- C. Gram dots -> REGISTERS ; stage D^T hi/lo ; dic out ; phase-A frags ; yA
  float ga0 = 0.0f, ga1 = 0.0f;
  {                                     // job tid (always < 666)
    int i = 0, rem = tid;
    while (rem >= TDIM - i) { rem -= TDIM - i; ++i; }
    const int j = i + rem;
    const float4* ri = (const float4*)(Df + i * SPS);
    const float4* rj = (const float4*)(Df + j * SPS);
    float a = 0.0f;
    #pragma unroll 7
    for (int k = 0; k < SPS / 4; ++k) {
      const float4 x = ri[k], y = rj[k];
      a += x.x * y.x + x.y * y.y + x.z * y.z + x.w * y.w;
    }
    ga0 = a;
  }
  if (tid < 154) {                      // job tid+512
    int i = 0, rem = tid + 512;
    while (rem >= TDIM - i) { rem -= TDIM - i; ++i; }
    const int j = i + rem;
    const float4* ri = (const float4*)(Df + i * SPS);
    const float4* rj = (const float4*)(Df + j * SPS);
    float a = 0.0f;
    #pragma unroll 7
    for (int k = 0; k < SPS / 4; ++k) {
      const float4 x = ri[k], y = rj[k];
      a += x.x * y.x + x.y * y.y + x.z * y.z + x.w * y.w;
    }
    ga1 = a;
  }
  for (int i = tid; i < TDIM * PDIM; i += 512) {
    const int t = i / PDIM, p = i - t * PDIM;
    const float v = Df[t * SPS + p];
    const half_t h = (half_t)v;
    *(half_t*)(smc + BY_DTH + p * (RKS * 2) + SWZ(p, t * 2)) = h;
    *(half_t*)(smc + BY_DTL + p * (RKS * 2) + SWZ(p, t * 2)) = (half_t)(v - (float)h);
    if (blk == 0) outDic[i] = v;
  }

  // phase-A ownership: 6 tiles (3 M x 1 N per wave), waves 0..5
  const int mtA = wave >> 1;
  const int ntA = wave & 1;
  half8 DhF[NKA], DlF[NKA];
  if (wave < 6) {                       // A-frags from fp32 Df (rows >= 36 are zero)
    const int row = 16 * mtA + ln;
    #pragma unroll
    for (int ks = 0; ks < NKA; ++ks) {
      half8 hh = {0,0,0,0,0,0,0,0}, ll = {0,0,0,0,0,0,0,0};
      if (row < TDIM) {
        const float4 f0 = *(const float4*)(Df + row * SPS + 32 * ks + 8 * q);
        const float4 f1 = *(const float4*)(Df + row * SPS + 32 * ks + 8 * q + 4);
        const float fa[8] = {f0.x, f0.y, f0.z, f0.w, f1.x, f1.y, f1.z, f1.w};
        #pragma unroll
        for (int e = 0; e < 8; ++e) {
          const half_t h = (half_t)fa[e];
          hh[e] = h;
          ll[e] = (half_t)(fa[e] - (float)h);
        }
      }
      DhF[ks] = hh;
      DlF[ks] = ll;
    }
  }
  // static Y (fp32) at phase-A C positions
  float yA[4];
  if (wave < 6) {
    const float* xb = xin + b * TDIM * NCOL;
    const int cl_ = 16 * ntA + ln;
    const int col = dh * DHALF + cl_;
    #pragma unroll
    for (int r = 0; r < 4; ++r) {
      const int t = 16 * mtA + 4 * q + r;
      yA[r] = (t < TDIM && cl_ < DHALF) ? xb[t * NCOL + col] : 0.0f;
    }
  }
  __syncthreads();

  // ---- Cb. write Gs from regs (Df rows >= 21 now clobbered; all Df reads done)
  {
    int i = 0, rem = tid;
    while (rem >= TDIM - i) { rem -= TDIM - i; ++i; }
    const int j = i + rem;
    Gs[i * GSTR + j] = ga0;
    Gs[j * GSTR + i] = ga0;
  }
  if (tid < 154) {
    int i = 0, rem = tid + 512;
    while (rem >= TDIM - i) { rem -= TDIM - i; ++i; }
    const int j = i + rem;
    Gs[i * GSTR + j] = ga1;
    Gs[j * GSTR + i] = ga1;
  }
  if (tid < 288) {                      // zero Gs pad cols 36..43 (stale Df)
    Gs[(tid >> 3) * GSTR + 36 + (tid & 7)] = 0.0f;
  }
  // phase-B ownership: 22 tiles (11 M x 2 N) over 8 waves; wave w owns f = w, w+8, w+16
  const int nTB = (wave < 6) ? 3 : 2;
  int ptB[3], ntB[3];
  #pragma unroll
  for (int k = 0; k < 3; ++k) {
    const int f = wave + 8 * k;
    const int nt = (f >= 11) ? 1 : 0;
    ntB[k] = nt;
    ptB[k] = f - 11 * nt;
  }
  half8 DtHF[3][NKB], DtLF[3][NKB];
  #pragma unroll
  for (int ti = 0; ti < 3; ++ti) {
    if (ti < nTB) {
      const int row = 16 * ptB[ti] + ln;
      #pragma unroll
      for (int ks = 0; ks < NKB; ++ks) {
        const int kb = (32 * ks + 8 * q) * 2;
        DtHF[ti][ks] = *(const half8*)(smc + BY_DTH + row * (RKS * 2) + SWZ(row, kb));
        DtLF[ti][ks] = *(const half8*)(smc + BY_DTL + row * (RKS * 2) + SWZ(row, kb));
      }
    }
  }
  __syncthreads();

  // ---- C2. G2 = G*G (Gs pads zero)
  for (int job = tid; job < 666; job += 512) {
    int i = 0, rem = job;
    while (rem >= TDIM - i) { rem -= TDIM - i; ++i; }
    const int j = i + rem;
    const float4* ri = (const float4*)(Gs + i * GSTR);
    const float4* rj = (const float4*)(Gs + j * GSTR);
    float a = 0.0f;
    #pragma unroll
    for (int k = 0; k < GSTR / 4; ++k) {
      const float4 x = ri[k], y = rj[k];
      a += x.x * y.x + x.y * y.y + x.z * y.z + x.w * y.w;
    }
    G2[i * GSTR + j] = a;
    G2[j * GSTR + i] = a;
  }
  __syncthreads();

  // ---- D2. wave 0: power iteration on G2 (readlane broadcasts, no barriers)
  if (wave == 0) {
    float g2r[36];
    #pragma unroll
    for (int j = 0; j < 36; ++j) g2r[j] = (lane < 36) ? G2[lane * GSTR + j] : 0.0f;
    float v = (lane < 36) ? 1.0f : 0.0f;
    for (int it = 0; it < PITER2; ++it) {
      const int vi = __float_as_int(v);
      float w0 = 0.0f, w1 = 0.0f;
      #pragma unroll
      for (int j = 0; j < 36; j += 2) {
        w0 = fmaf(g2r[j],     __int_as_float(__builtin_amdgcn_readlane(vi, j)),     w0);
        w1 = fmaf(g2r[j + 1], __int_as_float(__builtin_amdgcn_readlane(vi, j + 1)), w1);
      }
      float w = w0 + w1;
      if ((it & 3) == 3) {
        float s = w * w;
        #pragma unroll
        for (int off = 32; off > 0; off >>= 1) s += __shfl_xor(s, off, 64);
        w *= rsqrtf(s);
      }
      v = w;
    }
    // Rayleigh on ORIGINAL G (v unit from it=199 renorm)
    const int vi = __float_as_int(v);
    float w0 = 0.0f, w1 = 0.0f;
    #pragma unroll
    for (int j = 0; j < 36; j += 2) {
      const float gi0 = (lane < 36) ? Gs[lane * GSTR + j]     : 0.0f;
      const float gi1 = (lane < 36) ? Gs[lane * GSTR + j + 1] : 0.0f;
      w0 = fmaf(gi0, __int_as_float(__builtin_amdgcn_readlane(vi, j)),     w0);
      w1 = fmaf(gi1, __int_as_float(__builtin_amdgcn_readlane(vi, j + 1)), w1);
    }
    float num = v * (w0 + w1);
    #pragma unroll
    for (int off = 32; off > 0; off >>= 1) num += __shfl_xor(num, off, 64);
    if (lane == 0) {
      sc[0] = 1.0f / num;        // L_inv
      sc[1] = 0.1f / num;        // thr = lam_f * L_inv
    }
  }
  __syncthreads();

  // ---- E. kill Df alias in the loop regions: zero Y+R (y0 = 0, pads = 0)
  {
    unsigned int* z = (unsigned int*)smc;
    for (int i = tid; i < BY_GS / 4; i += 512) z[i] = 0u;
  }
  __syncthreads();
  const float L_inv = sc[0];
  const float thr = sc[1];

  float xR[3][4], yR[3][4];
  #pragma unroll
  for (int ti = 0; ti < 3; ++ti)
    #pragma unroll
    for (int r = 0; r < 4; ++r) { xR[ti][r] = 0.0f; yR[ti][r] = 0.0f; }

  float tk = 1.0f;

  // ---- F. FISTA loop (bank-conflict-free swizzled LDS, 2 blocks/CU)
  for (int it = 0; it < NITER; ++it) {
    // phase A: R = Y - D y   (M=48, N=32, K=192) — 4 indep MFMA chains of depth 3
    if (wave < 6) {
      floatx4 aH0 = {0.f,0.f,0.f,0.f}, aH1 = {0.f,0.f,0.f,0.f};
      floatx4 aL0 = {0.f,0.f,0.f,0.f}, aL1 = {0.f,0.f,0.f,0.f};
      const int n0 = 16 * ntA + ln;
      const char* yrow = smc + BY_Y + n0 * (YKS * 2);
      #pragma unroll
      for (int ks = 0; ks < NKA; ++ks) {
        const int kb = (32 * ks + 8 * q) * 2;
        const half8 b0 = *(const half8*)(yrow + SWZ(n0, kb));
        if (ks & 1) {
          aH1 = MFMA16(DhF[ks], b0, aH1, 0, 0, 0);
          aL1 = MFMA16(DlF[ks], b0, aL1, 0, 0, 0);
        } else {
          aH0 = MFMA16(DhF[ks], b0, aH0, 0, 0, 0);
          aL0 = MFMA16(DlF[ks], b0, aL0, 0, 0, 0);
        }
      }
      const int t0 = 16 * mtA + 4 * q;
      half4 hv;
      #pragma unroll
      for (int r = 0; r < 4; ++r)
        hv[r] = (half_t)(yA[r] - ((aH0[r] + aH1[r]) + (aL0[r] + aL1[r])));
      *(half4*)(smc + BY_R + n0 * (RKS * 2) + SWZ(n0, t0 * 2)) = hv;
    }
    __syncthreads();

    const float tnew = 0.5f * (1.0f + sqrtf(1.0f + 4.0f * tk * tk));
    const float ttf = (tk - 1.0f) / tnew;
    tk = tnew;

    // phase B: w = y + L_inv D^T R ; shrink + momentum  (M=176, N=32, K=64)
    {
      floatx4 accH[3], accL[3];
      #pragma unroll
      for (int ti = 0; ti < 3; ++ti) {
        accH[ti] = (floatx4){0.f,0.f,0.f,0.f};
        accL[ti] = (floatx4){0.f,0.f,0.f,0.f};
      }
      #pragma unroll
      for (int ti = 0; ti < 3; ++ti) {
        if (ti < nTB) {
          const int nr = 16 * ntB[ti] + ln;
          const char* rrow = smc + BY_R + nr * (RKS * 2);
          #pragma unroll
          for (int ks = 0; ks < NKB; ++ks) {
            const int kb = (32 * ks + 8 * q) * 2;
            const half8 rb = *(const half8*)(rrow + SWZ(nr, kb));
            accH[ti] = MFMA16(DtHF[ti][ks], rb, accH[ti], 0, 0, 0);
            accL[ti] = MFMA16(DtLF[ti][ks], rb, accL[ti], 0, 0, 0);
          }
        }
      }
      #pragma unroll
      for (int ti = 0; ti < 3; ++ti) {
        if (ti < nTB) {
          const int p0 = 16 * ptB[ti] + 4 * q;
          const int c  = 16 * ntB[ti] + ln;
          half4 hv;
          #pragma unroll
          for (int r = 0; r < 4; ++r) {
            const float w = yR[ti][r] + L_inv * (accH[ti][r] + accL[ti][r]);
            const float cl = fminf(fmaxf(w, -thr), thr);   // v_med3 clamp
            const float xn = w - cl;                        // softshrink
            const float yn = xn + ttf * (xn - xR[ti][r]);
            xR[ti][r] = xn;
            yR[ti][r] = yn;
            hv[r] = (half_t)yn;
          }
          *(half4*)(smc + BY_Y + c * (YKS * 2) + SWZ(c, p0 * 2)) = hv;
        }
      }
    }
    __syncthreads();
  }

  // ---- G. outputs: C = x_fin
  float* Cb = outC + b * PDIM * NCOL;
  #pragma unroll
  for (int ti = 0; ti < 3; ++ti) {
    if (ti < nTB) {
      const int cl_ = 16 * ntB[ti] + ln;
      if (cl_ < DHALF) {
        const int col = dh * DHALF + cl_;
        #pragma unroll
        for (int r = 0; r < 4; ++r) {
          const int p = 16 * ptB[ti] + 4 * q + r;
          if (p < PDIM) Cb[p * NCOL + col] = xR[ti][r];
        }
      }
    }
  }
  // reconst = D @ C : restage x into Y (fp16), rerun phase-A GEMM
  #pragma unroll
  for (int ti = 0; ti < 3; ++ti) {
    if (ti < nTB) {
      const int p0 = 16 * ptB[ti] + 4 * q;
      const int c  = 16 * ntB[ti] + ln;
      half4 hv;
      #pragma unroll
      for (int r = 0; r < 4; ++r) hv[r] = (half_t)xR[ti][r];
      *(half4*)(smc + BY_Y + c * (YKS * 2) + SWZ(c, p0 * 2)) = hv;
    }
  }
  __syncthreads();
  if (wave < 6) {
    floatx4 aH0 = {0.f,0.f,0.f,0.f}, aH1 = {0.f,0.f,0.f,0.f};
    floatx4 aL0 = {0.f,0.f,0.f,0.f}, aL1 = {0.f,0.f,0.f,0.f};
    const int n0 = 16 * ntA + ln;
    const char* yrow = smc + BY_Y + n0 * (YKS * 2);
    #pragma unroll
    for (int ks = 0; ks < NKA; ++ks) {
      const int kb = (32 * ks + 8 * q) * 2;
      const half8 b0 = *(const half8*)(yrow + SWZ(n0, kb));
      if (ks & 1) {
        aH1 = MFMA16(DhF[ks], b0, aH1, 0, 0, 0);
        aL1 = MFMA16(DlF[ks], b0, aL1, 0, 0, 0);
      } else {
        aH0 = MFMA16(DhF[ks], b0, aH0, 0, 0, 0);
        aL0 = MFMA16(DlF[ks], b0, aL0, 0, 0, 0);
      }
    }
    float* Rb = outR + b * TDIM * NCOL;
    const int cl_ = 16 * ntA + ln;
    if (cl_ < DHALF) {
      const int col = dh * DHALF + cl_;
      const int t0 = 16 * mtA + 4 * q;
      #pragma unroll
      for (int r = 0; r < 4; ++r) {
        const int t = t0 + r;
        if (t < TDIM) Rb[t * NCOL + col] = (aH0[r] + aH1[r]) + (aL0[r] + aL1[r]);
      }
    }
  }
}

// ---------------- launch --------------------------------------------------------------

extern "C" void kernel_launch(void* const* d_in, const int* in_sizes, int n_in,
                              void* d_out, int out_size, void* d_ws, size_t ws_size,
                              hipStream_t stream) {
  const float* x     = (const float*)d_in[0];   // (256, 36, 50)
  const float* rho   = (const float*)d_in[1];   // (80,)
  const float* theta = (const float*)d_in[2];   // (80,)

  float* out    = (float*)d_out;
  float* outC   = out;                              // 256*161*50
  float* outDic = out + 256 * PDIM * NCOL;          // 36*161
  float* outR   = outDic + TDIM * PDIM;             // 256*36*50

  hipLaunchKernelGGL(dan_kernel, dim3(512), dim3(512), LDS_TOTAL, stream,
                     x, rho, theta, outC, outDic, outR);
}

// Round 3
// 285.932 us; speedup vs baseline: 1.3130x; 1.3130x over previous
//
#include <hip/hip_runtime.h>
#include <math.h>

typedef _Float16 half_t;
typedef __attribute__((ext_vector_type(8))) _Float16 half8;
typedef __attribute__((ext_vector_type(4))) _Float16 half4;
typedef __attribute__((ext_vector_type(4))) float floatx4;

#define TDIM 36
#define PDIM 161        // 2*80+1 atoms
#define NCOL 50
#define NITER 100
#define PITER2 200      // power steps on G^2 == 400 on G (proven accuracy)

// GEMM geometry: phase A M=48,N=64,K=192 (12 tiles) ; phase B M=176,N=64,K=64 (44 tiles)
#define NKA 6
#define NKB 2
#define GSTR 44
#define SPS 196         // Df (fp32) row stride (dwords)

// row strides in BYTES (all multiples of 16 -> swizzled b128 stays aligned)
#define YROW 384        // Y^T  [64][192] half
#define RROW 128        // R^T  [64][64] half
#define DROW 384        // DH/DL [48][192] half (phase-A A-operand layout)
#define TROW 128        // DtH/DtL [176][64] half (phase-B A-operand layout)

// XOR swizzle: spread same-column reads across 8 rows -> 8 distinct 16B slots
#define SWZ(row, byteoff) ((byteoff) ^ (((row) & 7) << 4))

// ---- byte-offset LDS map: 127,376 B, 1 block/CU, NO aliasing except Df over Y+R ----
#define BY_Y    0                      // 24,576
#define BY_R    24576                  //  8,192
#define BY_SC   32768                  //     16
#define BY_DH   32784                  // 18,432
#define BY_DL   51216                  // 18,432
#define BY_DTH  69648                  // 22,528
#define BY_DTL  92176                  // 22,528
#define BY_GS   114704                 //  6,336
#define BY_G2   121040                 //  6,336
#define LDS_TOTAL 127376
// setup alias: Df fp32 [36][196] = 28,224 B over Y+R (re-zeroed before the loop)

#define MFMA16 __builtin_amdgcn_mfma_f32_16x16x32_f16

__global__ __launch_bounds__(1024, 4)
void dan_kernel(const float* __restrict__ xin, const float* __restrict__ rho,
                const float* __restrict__ theta, float* __restrict__ outC,
                float* __restrict__ outDic, float* __restrict__ outR)
{
  extern __shared__ char smc[];
  float*  sc  = (float*)(smc + BY_SC);
  float*  Gs  = (float*)(smc + BY_GS);
  float*  G2  = (float*)(smc + BY_G2);
  float*  Df  = (float*)(smc + BY_Y);   // setup alias

  const int tid = threadIdx.x;
  const int b = blockIdx.x;
  const int wave = tid >> 6, lane = tid & 63;
  const int q = lane >> 4, ln = lane & 15;

  // ---- A. zero all LDS (pads must be 0)
  {
    unsigned int* z = (unsigned int*)smc;
    for (int i = tid; i < LDS_TOTAL / 4; i += 1024) z[i] = 0u;
  }
  __syncthreads();

  // ---- B. build normalized dictionary (fp32, one column per thread)
  if (tid < PDIM) {
    if (tid == 0) {
      for (int t = 0; t < TDIM; ++t) Df[t * SPS] = 1.0f;
    } else {
      const bool is_sin = tid > 80;
      const int n = is_sin ? (tid - 81) : (tid - 1);
      const float rr = 0.001f + 1.149f / (1.0f + expf(-rho[n]));
      const float th = 3.14159265358979f / (1.0f + expf(-theta[n]));
      const float lr = logf(rr);
      float s2 = 0.0f;
      for (int t = 0; t < TDIM; ++t) {
        const float ft = (float)t;
        const float val = expf(ft * lr) * (is_sin ? sinf(ft * th) : cosf(ft * th));
        Df[t * SPS + tid] = val;
        s2 += val * val;
      }
      const float inv = 1.0f / sqrtf(s2);
      for (int t = 0; t < TDIM; ++t) Df[t * SPS + tid] *= inv;
    }
  }
  __syncthreads();

  // ---- C. Gram -> Gs (disjoint from Df) ; stage DH/DL + DtH/DtL ; dic out
  if (tid < 666) {                      // 666 = 36*37/2
    int i = 0, rem = tid;
    while (rem >= TDIM - i) { rem -= TDIM - i; ++i; }
    const int j = i + rem;
    const float4* ri = (const float4*)(Df + i * SPS);
    const float4* rj = (const float4*)(Df + j * SPS);
    float a = 0.0f;
    #pragma unroll 7
    for (int k = 0; k < SPS / 4; ++k) {
      const float4 x = ri[k], y = rj[k];
      a += x.x * y.x + x.y * y.y + x.z * y.z + x.w * y.w;
    }
    Gs[i * GSTR + j] = a;
    Gs[j * GSTR + i] = a;
  }
  for (int i = tid; i < TDIM * PDIM; i += 1024) {
    const int t = i / PDIM, p = i - t * PDIM;
    const float v = Df[t * SPS + p];
    const half_t h = (half_t)v;
    const half_t l = (half_t)(v - (float)h);
    *(half_t*)(smc + BY_DTH + p * TROW + SWZ(p, t * 2)) = h;
    *(half_t*)(smc + BY_DTL + p * TROW + SWZ(p, t * 2)) = l;
    *(half_t*)(smc + BY_DH  + t * DROW + SWZ(t, p * 2)) = h;
    *(half_t*)(smc + BY_DL  + t * DROW + SWZ(t, p * 2)) = l;
    if (b == 0) outDic[i] = v;
  }

  // ---- ownership maps
  const int mtA = wave >> 2;            // phase A: waves 0..11, 3 M x 4 N
  const int ntA = wave & 3;
  const int baseB = wave >> 2;          // phase B: nt const per wave; pt = base+4k
  const int ntB = wave & 3;
  const int nTB = (baseB == 3) ? 2 : 3;

  // static Y (fp32) at phase-A C positions
  float yA[4];
  if (wave < 12) {
    const float* xb = xin + b * TDIM * NCOL;
    const int c = 16 * ntA + ln;
    #pragma unroll
    for (int r = 0; r < 4; ++r) {
      const int t = 16 * mtA + 4 * q + r;
      yA[r] = (t < TDIM && c < NCOL) ? xb[t * NCOL + c] : 0.0f;
    }
  }
  __syncthreads();

  // ---- C2. G2 = G*G (Gs pads zero from initial memset)
  if (tid < 666) {
    int i = 0, rem = tid;
    while (rem >= TDIM - i) { rem -= TDIM - i; ++i; }
    const int j = i + rem;
    const float4* ri = (const float4*)(Gs + i * GSTR);
    const float4* rj = (const float4*)(Gs + j * GSTR);
    float a = 0.0f;
    #pragma unroll
    for (int k = 0; k < GSTR / 4; ++k) {
      const float4 x = ri[k], y = rj[k];
      a += x.x * y.x + x.y * y.y + x.z * y.z + x.w * y.w;
    }
    G2[i * GSTR + j] = a;
    G2[j * GSTR + i] = a;
  }
  __syncthreads();

  // ---- D2. wave 0: power iteration on G2 ; waves 1..15: zero Y+R (kills Df alias)
  if (wave == 0) {
    float g2r[36];
    #pragma unroll
    for (int j = 0; j < 36; ++j) g2r[j] = (lane < 36) ? G2[lane * GSTR + j] : 0.0f;
    float v = (lane < 36) ? 1.0f : 0.0f;
    for (int it = 0; it < PITER2; ++it) {
      const int vi = __float_as_int(v);
      float w0 = 0.0f, w1 = 0.0f, w2 = 0.0f, w3 = 0.0f;
      #pragma unroll
      for (int j = 0; j < 36; j += 4) {
        w0 = fmaf(g2r[j],     __int_as_float(__builtin_amdgcn_readlane(vi, j)),     w0);
        w1 = fmaf(g2r[j + 1], __int_as_float(__builtin_amdgcn_readlane(vi, j + 1)), w1);
        w2 = fmaf(g2r[j + 2], __int_as_float(__builtin_amdgcn_readlane(vi, j + 2)), w2);
        w3 = fmaf(g2r[j + 3], __int_as_float(__builtin_amdgcn_readlane(vi, j + 3)), w3);
      }
      float w = (w0 + w1) + (w2 + w3);
      if ((it & 3) == 3) {
        float s = w * w;
        #pragma unroll
        for (int off = 32; off > 0; off >>= 1) s += __shfl_xor(s, off, 64);
        w *= rsqrtf(s);
      }
      v = w;
    }
    // Rayleigh on ORIGINAL G (v unit from final renorm)
    const int vi = __float_as_int(v);
    float w0 = 0.0f, w1 = 0.0f;
    #pragma unroll
    for (int j = 0; j < 36; j += 2) {
      const float gi0 = (lane < 36) ? Gs[lane * GSTR + j]     : 0.0f;
      const float gi1 = (lane < 36) ? Gs[lane * GSTR + j + 1] : 0.0f;
      w0 = fmaf(gi0, __int_as_float(__builtin_amdgcn_readlane(vi, j)),     w0);
      w1 = fmaf(gi1, __int_as_float(__builtin_amdgcn_readlane(vi, j + 1)), w1);
    }
    float num = v * (w0 + w1);
    #pragma unroll
    for (int off = 32; off > 0; off >>= 1) num += __shfl_xor(num, off, 64);
    if (lane == 0) {
      sc[0] = 1.0f / num;        // L_inv
      sc[1] = 0.1f / num;        // thr = lam_f * L_inv
    }
  } else {
    unsigned int* z = (unsigned int*)smc;
    for (int i = tid - 64; i < 32768 / 4; i += 960) z[i] = 0u;   // Y+R zero
  }
  __syncthreads();
  const float L_inv = sc[0];
  const float thr = sc[1];

  float xR[3][4], yR[3][4];
  #pragma unroll
  for (int ti = 0; ti < 3; ++ti)
    #pragma unroll
    for (int r = 0; r < 4; ++r) { xR[ti][r] = 0.0f; yR[ti][r] = 0.0f; }

  float tk = 1.0f;

  // ---- F. FISTA loop: all fragments re-read from swizzled LDS (low regs, 4 waves/SIMD)
  for (int it = 0; it < NITER; ++it) {
    // phase A (waves 0..11): R = Y - D y  (M=48, N=64, K=192)
    if (wave < 12) {
      floatx4 aH0 = {0.f,0.f,0.f,0.f}, aH1 = {0.f,0.f,0.f,0.f};
      floatx4 aL0 = {0.f,0.f,0.f,0.f}, aL1 = {0.f,0.f,0.f,0.f};
      const int n0 = 16 * ntA + ln;
      const int rowA = 16 * mtA + ln;
      const char* yrow = smc + BY_Y  + n0   * YROW;
      const char* dh   = smc + BY_DH + rowA * DROW;
      const char* dl   = smc + BY_DL + rowA * DROW;
      #pragma unroll
      for (int ks = 0; ks < NKA; ++ks) {
        const int kb = (32 * ks + 8 * q) * 2;
        const half8 b0 = *(const half8*)(yrow + SWZ(n0, kb));
        const half8 ah = *(const half8*)(dh + SWZ(rowA, kb));
        const half8 al = *(const half8*)(dl + SWZ(rowA, kb));
        if (ks & 1) {
          aH1 = MFMA16(ah, b0, aH1, 0, 0, 0);
          aL1 = MFMA16(al, b0, aL1, 0, 0, 0);
        } else {
          aH0 = MFMA16(ah, b0, aH0, 0, 0, 0);
          aL0 = MFMA16(al, b0, aL0, 0, 0, 0);
        }
      }
      const int t0 = 16 * mtA + 4 * q;
      half4 hv;
      #pragma unroll
      for (int r = 0; r < 4; ++r)
        hv[r] = (half_t)(yA[r] - ((aH0[r] + aH1[r]) + (aL0[r] + aL1[r])));
      *(half4*)(smc + BY_R + n0 * RROW + SWZ(n0, t0 * 2)) = hv;
    }
    __syncthreads();

    const float tnew = 0.5f * (1.0f + sqrtf(1.0f + 4.0f * tk * tk));
    const float ttf = (tk - 1.0f) / tnew;
    tk = tnew;

    // phase B (all 16 waves): w = y + L_inv D^T R ; shrink + momentum (M=176, N=64, K=64)
    {
      const int nr = 16 * ntB + ln;
      const char* rrow = smc + BY_R + nr * RROW;
      const half8 rb0 = *(const half8*)(rrow + SWZ(nr, (8 * q) * 2));
      const half8 rb1 = *(const half8*)(rrow + SWZ(nr, (64 + 16 * q) ));   // (32+8q)*2
      floatx4 accH[3], accL[3];
      #pragma unroll
      for (int ti = 0; ti < 3; ++ti) {
        accH[ti] = (floatx4){0.f,0.f,0.f,0.f};
        accL[ti] = (floatx4){0.f,0.f,0.f,0.f};
      }
      #pragma unroll
      for (int ti = 0; ti < 3; ++ti) {
        if (ti < nTB) {
          const int pt = baseB + 4 * ti;
          const int rowT = 16 * pt + ln;
          const char* th_ = smc + BY_DTH + rowT * TROW;
          const char* tl_ = smc + BY_DTL + rowT * TROW;
          const int kb0 = (8 * q) * 2, kb1 = (32 + 8 * q) * 2;
          const half8 th0 = *(const half8*)(th_ + SWZ(rowT, kb0));
          const half8 tl0 = *(const half8*)(tl_ + SWZ(rowT, kb0));
          const half8 th1 = *(const half8*)(th_ + SWZ(rowT, kb1));
          const half8 tl1 = *(const half8*)(tl_ + SWZ(rowT, kb1));
          accH[ti] = MFMA16(th0, rb0, accH[ti], 0, 0, 0);
          accL[ti] = MFMA16(tl0, rb0, accL[ti], 0, 0, 0);
          accH[ti] = MFMA16(th1, rb1, accH[ti], 0, 0, 0);
          accL[ti] = MFMA16(tl1, rb1, accL[ti], 0, 0, 0);
        }
      }
      #pragma unroll
      for (int ti = 0; ti < 3; ++ti) {
        if (ti < nTB) {
          const int pt = baseB + 4 * ti;
          const int p0 = 16 * pt + 4 * q;
          half4 hv;
          #pragma unroll
          for (int r = 0; r < 4; ++r) {
            const float w = yR[ti][r] + L_inv * (accH[ti][r] + accL[ti][r]);
            const float cl = fminf(fmaxf(w, -thr), thr);   // v_med3 clamp
            const float xn = w - cl;                        // softshrink
            const float yn = xn + ttf * (xn - xR[ti][r]);
            xR[ti][r] = xn;
            yR[ti][r] = yn;
            hv[r] = (half_t)yn;
          }
          *(half4*)(smc + BY_Y + nr * YROW + SWZ(nr, p0 * 2)) = hv;
        }
      }
    }
    __syncthreads();
  }

  // ---- G. outputs: C = x_fin
  float* Cb = outC + b * PDIM * NCOL;
  {
    const int c = 16 * ntB + ln;
    if (c < NCOL) {
      #pragma unroll
      for (int ti = 0; ti < 3; ++ti) {
        if (ti < nTB) {
          const int pt = baseB + 4 * ti;
          #pragma unroll
          for (int r = 0; r < 4; ++r) {
            const int p = 16 * pt + 4 * q + r;
            if (p < PDIM) Cb[p * NCOL + c] = xR[ti][r];
          }
        }
      }
    }
  }
  // reconst = D @ C : restage x into Y (fp16), rerun phase-A GEMM
  {
    const int nr = 16 * ntB + ln;
    #pragma unroll
    for (int ti = 0; ti < 3; ++ti) {
      if (ti < nTB) {
        const int pt = baseB + 4 * ti;
        const int p0 = 16 * pt + 4 * q;
        half4 hv;
        #pragma unroll
        for (int r = 0; r < 4; ++r) hv[r] = (half_t)xR[ti][r];
        *(half4*)(smc + BY_Y + nr * YROW + SWZ(nr, p0 * 2)) = hv;
      }
    }
  }
  __syncthreads();
  if (wave < 12) {
    floatx4 aH0 = {0.f,0.f,0.f,0.f}, aH1 = {0.f,0.f,0.f,0.f};
    floatx4 aL0 = {0.f,0.f,0.f,0.f}, aL1 = {0.f,0.f,0.f,0.f};
    const int n0 = 16 * ntA + ln;
    const int rowA = 16 * mtA + ln;
    const char* yrow = smc + BY_Y  + n0   * YROW;
    const char* dh   = smc + BY_DH + rowA * DROW;
    const char* dl   = smc + BY_DL + rowA * DROW;
    #pragma unroll
    for (int ks = 0; ks < NKA; ++ks) {
      const int kb = (32 * ks + 8 * q) * 2;
      const half8 b0 = *(const half8*)(yrow + SWZ(n0, kb));
      const half8 ah = *(const half8*)(dh + SWZ(rowA, kb));
      const half8 al = *(const half8*)(dl + SWZ(rowA, kb));
      if (ks & 1) {
        aH1 = MFMA16(ah, b0, aH1, 0, 0, 0);
        aL1 = MFMA16(al, b0, aL1, 0, 0, 0);
      } else {
        aH0 = MFMA16(ah, b0, aH0, 0, 0, 0);
        aL0 = MFMA16(al, b0, aL0, 0, 0, 0);
      }
    }
    float* Rb = outR + b * TDIM * NCOL;
    const int c = 16 * ntA + ln;
    if (c < NCOL) {
      const int t0 = 16 * mtA + 4 * q;
      #pragma unroll
      for (int r = 0; r < 4; ++r) {
        const int t = t0 + r;
        if (t < TDIM) Rb[t * NCOL + c] = (aH0[r] + aH1[r]) + (aL0[r] + aL1[r]);
      }
    }
  }
}

// ---------------- launch --------------------------------------------------------------

extern "C" void kernel_launch(void* const* d_in, const int* in_sizes, int n_in,
                              void* d_out, int out_size, void* d_ws, size_t ws_size,
                              hipStream_t stream) {
  const float* x     = (const float*)d_in[0];   // (256, 36, 50)
  const float* rho   = (const float*)d_in[1];   // (80,)
  const float* theta = (const float*)d_in[2];   // (80,)

  float* out    = (float*)d_out;
  float* outC   = out;                              // 256*161*50
  float* outDic = out + 256 * PDIM * NCOL;          // 36*161
  float* outR   = outDic + TDIM * PDIM;             // 256*36*50

  hipLaunchKernelGGL(dan_kernel, dim3(256), dim3(1024), LDS_TOTAL, stream,
                     x, rho, theta, outC, outDic, outR);
}

// Round 4
// 224.768 us; speedup vs baseline: 1.6703x; 1.2721x over previous
//
#include <hip/hip_runtime.h>
#include <math.h>

typedef _Float16 half_t;
typedef __attribute__((ext_vector_type(8))) _Float16 half8;
typedef __attribute__((ext_vector_type(4))) _Float16 half4;
typedef __attribute__((ext_vector_type(4))) float floatx4;

#define TDIM 36
#define PDIM 161        // 2*80+1 atoms
#define NCOL 50
#define NITER 100
#define PITER8 50       // power steps on G^8 == 400 on G (same total as proven config)

// GEMM geometry: phase A M=48,N=64,K=192 (12 tiles, 1/wave) ;
//                phase B M=176,N=64,K=64 (11 pt x 4 nt; wave w<11 owns pt=w, all 4 nt)
#define NKA 6
#define GSTR 44
#define SPS 196         // Df (fp32) row stride (dwords)

// row strides in BYTES
#define YROW 384        // Y^T [64][192] half
#define RROW 128        // R^T [64][64] half

// XOR swizzle: spread same-column reads across 8 rows -> 8 distinct 16B slots
#define SWZ(row, byteoff) ((byteoff) ^ (((row) & 7) << 4))

// ---- byte-offset LDS map: 51,792 B ----
#define BY_Y    0                      // 24,576
#define BY_R    24576                  //  8,192
#define BY_LRTH 28672                  //  1,288 (inside R region, past Df end 28,224)
#define BY_SC   32768                  //     16
#define BY_GS   32784                  //  6,336
#define BY_G2   39120                  //  6,336  (holds G^2, later overwritten by G^8)
#define BY_G4   45456                  //  6,336
#define LDS_TOTAL 51792
// setup alias: Df fp32 [36][196] = 28,224 B over Y + head of R (re-zeroed before loop)

#define MFMA16 __builtin_amdgcn_mfma_f32_16x16x32_f16

__global__ __launch_bounds__(768, 3)
void dan_kernel(const float* __restrict__ xin, const float* __restrict__ rho,
                const float* __restrict__ theta, float* __restrict__ outC,
                float* __restrict__ outDic, float* __restrict__ outR)
{
  extern __shared__ char smc[];
  float*  sc   = (float*)(smc + BY_SC);
  float*  Gs   = (float*)(smc + BY_GS);
  float*  G2   = (float*)(smc + BY_G2);
  float*  G4   = (float*)(smc + BY_G4);
  float*  Df   = (float*)(smc + BY_Y);    // setup alias
  float*  lrth = (float*)(smc + BY_LRTH); // [161] lr, [161] th (setup only)

  const int tid = threadIdx.x;
  const int b = blockIdx.x;
  const int wave = tid >> 6, lane = tid & 63;
  const int q = lane >> 4, ln = lane & 15;

  // ---- A. zero all LDS (pads must be 0)
  {
    unsigned int* z = (unsigned int*)smc;
    for (int i = tid; i < LDS_TOTAL / 4; i += 768) z[i] = 0u;
  }
  __syncthreads();

  // ---- B0. per-atom lr/th (161 threads, 2 transcendentals each)
  if (tid >= 1 && tid < PDIM) {
    const bool is_sin = tid > 80;
    const int n = is_sin ? (tid - 81) : (tid - 1);
    lrth[tid]       = logf(0.001f + 1.149f / (1.0f + expf(-rho[n])));
    lrth[161 + tid] = 3.14159265358979f / (1.0f + expf(-theta[n]));
  }
  __syncthreads();

  // ---- B1. raw dictionary, parallel over all (t,p) jobs
  for (int i = tid; i < TDIM * PDIM; i += 768) {
    const int t = i / PDIM, p = i - t * PDIM;
    float val;
    if (p == 0) {
      val = 1.0f;
    } else {
      const float ft = (float)t;
      const float e = expf(ft * lrth[p]);
      const float ang = ft * lrth[161 + p];
      val = e * (p > 80 ? sinf(ang) : cosf(ang));
    }
    Df[t * SPS + p] = val;
  }
  __syncthreads();

  // ---- B2. column-normalize (atoms 1..160)
  if (tid >= 1 && tid < PDIM) {
    float s2 = 0.0f;
    for (int t = 0; t < TDIM; ++t) {
      const float v = Df[t * SPS + tid];
      s2 += v * v;
    }
    const float inv = 1.0f / sqrtf(s2);
    for (int t = 0; t < TDIM; ++t) Df[t * SPS + tid] *= inv;
  }
  __syncthreads();

  // ---- C. Gram -> Gs ; dic out ; load ALL MFMA fragments to registers
  if (tid < 666) {                      // 666 = 36*37/2
    int i = 0, rem = tid;
    while (rem >= TDIM - i) { rem -= TDIM - i; ++i; }
    const int j = i + rem;
    const float4* ri = (const float4*)(Df + i * SPS);
    const float4* rj = (const float4*)(Df + j * SPS);
    float a = 0.0f;
    #pragma unroll 7
    for (int k = 0; k < SPS / 4; ++k) {
      const float4 x = ri[k], y = rj[k];
      a += x.x * y.x + x.y * y.y + x.z * y.z + x.w * y.w;
    }
    Gs[i * GSTR + j] = a;
    Gs[j * GSTR + i] = a;
  }
  if (b == 0) {
    for (int i = tid; i < TDIM * PDIM; i += 768) {
      const int t = i / PDIM, p = i - t * PDIM;
      outDic[i] = Df[t * SPS + p];
    }
  }

  // ownership maps
  const int mtA = wave >> 2;            // phase A: 3 mt x 4 nt, one tile per wave
  const int ntA = wave & 3;

  // phase-A A-fragments (D hi/lo); rows >= 36 are zero
  half8 DhF[NKA], DlF[NKA];
  {
    const int row = 16 * mtA + ln;
    #pragma unroll
    for (int ks = 0; ks < NKA; ++ks) {
      half8 hh = {0,0,0,0,0,0,0,0}, ll = {0,0,0,0,0,0,0,0};
      if (row < TDIM) {
        const float4 f0 = *(const float4*)(Df + row * SPS + 32 * ks + 8 * q);
        const float4 f1 = *(const float4*)(Df + row * SPS + 32 * ks + 8 * q + 4);
        const float fa[8] = {f0.x, f0.y, f0.z, f0.w, f1.x, f1.y, f1.z, f1.w};
        #pragma unroll
        for (int e = 0; e < 8; ++e) {
          const half_t h = (half_t)fa[e];
          hh[e] = h;
          ll[e] = (half_t)(fa[e] - (float)h);
        }
      }
      DhF[ks] = hh;
      DlF[ks] = ll;
    }
  }
  // phase-B A-fragments (D^T hi/lo), direct transposed read from Df
  half8 DtH[2], DtL[2];
  if (wave < 11) {
    const int prow = 16 * wave + ln;    // atom index; cols >=161 of Df are zero
    #pragma unroll
    for (int ks = 0; ks < 2; ++ks) {
      half8 hh, ll;
      #pragma unroll
      for (int e = 0; e < 8; ++e) {
        const int t = 32 * ks + 8 * q + e;
        const float v = (t < TDIM) ? Df[t * SPS + prow] : 0.0f;
        const half_t h = (half_t)v;
        hh[e] = h;
        ll[e] = (half_t)(v - (float)h);
      }
      DtH[ks] = hh;
      DtL[ks] = ll;
    }
  }
  // static Y (fp32) at phase-A C positions
  float yA[4];
  {
    const float* xb = xin + b * TDIM * NCOL;
    const int c = 16 * ntA + ln;
    #pragma unroll
    for (int r = 0; r < 4; ++r) {
      const int t = 16 * mtA + 4 * q + r;
      yA[r] = (t < TDIM && c < NCOL) ? xb[t * NCOL + c] : 0.0f;
    }
  }
  __syncthreads();

  // ---- C2. G2 = G*G  (pads of all Gram buffers are zero)
  if (tid < 666) {
    int i = 0, rem = tid;
    while (rem >= TDIM - i) { rem -= TDIM - i; ++i; }
    const int j = i + rem;
    const float4* ri = (const float4*)(Gs + i * GSTR);
    const float4* rj = (const float4*)(Gs + j * GSTR);
    float a = 0.0f;
    #pragma unroll
    for (int k = 0; k < GSTR / 4; ++k) {
      const float4 x = ri[k], y = rj[k];
      a += x.x * y.x + x.y * y.y + x.z * y.z + x.w * y.w;
    }
    G2[i * GSTR + j] = a;
    G2[j * GSTR + i] = a;
  }
  __syncthreads();
  // ---- C3. G4 = G2*G2
  if (tid < 666) {
    int i = 0, rem = tid;
    while (rem >= TDIM - i) { rem -= TDIM - i; ++i; }
    const int j = i + rem;
    const float4* ri = (const float4*)(G2 + i * GSTR);
    const float4* rj = (const float4*)(G2 + j * GSTR);
    float a = 0.0f;
    #pragma unroll
    for (int k = 0; k < GSTR / 4; ++k) {
      const float4 x = ri[k], y = rj[k];
      a += x.x * y.x + x.y * y.y + x.z * y.z + x.w * y.w;
    }
    G4[i * GSTR + j] = a;
    G4[j * GSTR + i] = a;
  }
  __syncthreads();
  // ---- C4. G8 = G4*G4 -> overwrite G2 buffer
  if (tid < 666) {
    int i = 0, rem = tid;
    while (rem >= TDIM - i) { rem -= TDIM - i; ++i; }
    const int j = i + rem;
    const float4* ri = (const float4*)(G4 + i * GSTR);
    const float4* rj = (const float4*)(G4 + j * GSTR);
    float a = 0.0f;
    #pragma unroll
    for (int k = 0; k < GSTR / 4; ++k) {
      const float4 x = ri[k], y = rj[k];
      a += x.x * y.x + x.y * y.y + x.z * y.z + x.w * y.w;
    }
    G2[i * GSTR + j] = a;
    G2[j * GSTR + i] = a;
  }
  __syncthreads();

  // ---- D2. wave 0: power iteration on G8 (renorm every iter) ; others: zero Y+R
  if (wave == 0) {
    float g8r[36];
    #pragma unroll
    for (int j = 0; j < 36; ++j) g8r[j] = (lane < 36) ? G2[lane * GSTR + j] : 0.0f;
    float v = (lane < 36) ? 1.0f : 0.0f;
    for (int it = 0; it < PITER8; ++it) {
      const int vi = __float_as_int(v);
      float w0 = 0.0f, w1 = 0.0f, w2 = 0.0f, w3 = 0.0f;
      #pragma unroll
      for (int j = 0; j < 36; j += 4) {
        w0 = fmaf(g8r[j],     __int_as_float(__builtin_amdgcn_readlane(vi, j)),     w0);
        w1 = fmaf(g8r[j + 1], __int_as_float(__builtin_amdgcn_readlane(vi, j + 1)), w1);
        w2 = fmaf(g8r[j + 2], __int_as_float(__builtin_amdgcn_readlane(vi, j + 2)), w2);
        w3 = fmaf(g8r[j + 3], __int_as_float(__builtin_amdgcn_readlane(vi, j + 3)), w3);
      }
      float w = (w0 + w1) + (w2 + w3);
      float s = w * w;
      #pragma unroll
      for (int off = 32; off > 0; off >>= 1) s += __shfl_xor(s, off, 64);
      v = w * rsqrtf(s);
    }
    // Rayleigh on ORIGINAL G (v is unit)
    const int vi = __float_as_int(v);
    float w0 = 0.0f, w1 = 0.0f;
    #pragma unroll
    for (int j = 0; j < 36; j += 2) {
      const float gi0 = (lane < 36) ? Gs[lane * GSTR + j]     : 0.0f;
      const float gi1 = (lane < 36) ? Gs[lane * GSTR + j + 1] : 0.0f;
      w0 = fmaf(gi0, __int_as_float(__builtin_amdgcn_readlane(vi, j)),     w0);
      w1 = fmaf(gi1, __int_as_float(__builtin_amdgcn_readlane(vi, j + 1)), w1);
    }
    float num = v * (w0 + w1);
    #pragma unroll
    for (int off = 32; off > 0; off >>= 1) num += __shfl_xor(num, off, 64);
    if (lane == 0) {
      sc[0] = 1.0f / num;        // L_inv
      sc[1] = 0.1f / num;        // thr = lam_f * L_inv
    }
  } else {
    unsigned int* z = (unsigned int*)smc;
    for (int i = tid - 64; i < 32768 / 4; i += 704) z[i] = 0u;   // kill Df alias; y0=0
  }
  __syncthreads();
  const float L_inv = sc[0];
  const float thr = sc[1];

  float xR[4][4], yR[4][4];             // [nt][r], valid for wave < 11
  #pragma unroll
  for (int nt = 0; nt < 4; ++nt)
    #pragma unroll
    for (int r = 0; r < 4; ++r) { xR[nt][r] = 0.0f; yR[nt][r] = 0.0f; }

  float tk = 1.0f;

  // ---- F. FISTA loop: all constant fragments in registers; only Y/R hit LDS
  for (int it = 0; it < NITER; ++it) {
    // phase A (all 12 waves): R = Y - D y   (M=48, N=64, K=192)
    {
      floatx4 aH0 = {0.f,0.f,0.f,0.f}, aH1 = {0.f,0.f,0.f,0.f};
      floatx4 aL0 = {0.f,0.f,0.f,0.f}, aL1 = {0.f,0.f,0.f,0.f};
      const int n0 = 16 * ntA + ln;
      const char* yrow = smc + BY_Y + n0 * YROW;
      #pragma unroll
      for (int ks = 0; ks < NKA; ++ks) {
        const int kb = (32 * ks + 8 * q) * 2;
        const half8 b0 = *(const half8*)(yrow + SWZ(n0, kb));
        if (ks & 1) {
          aH1 = MFMA16(DhF[ks], b0, aH1, 0, 0, 0);
          aL1 = MFMA16(DlF[ks], b0, aL1, 0, 0, 0);
        } else {
          aH0 = MFMA16(DhF[ks], b0, aH0, 0, 0, 0);
          aL0 = MFMA16(DlF[ks], b0, aL0, 0, 0, 0);
        }
      }
      const int t0 = 16 * mtA + 4 * q;
      half4 hv;
      #pragma unroll
      for (int r = 0; r < 4; ++r)
        hv[r] = (half_t)(yA[r] - ((aH0[r] + aH1[r]) + (aL0[r] + aL1[r])));
      *(half4*)(smc + BY_R + n0 * RROW + SWZ(n0, t0 * 2)) = hv;
    }
    __syncthreads();

    const float tnew = 0.5f * (1.0f + sqrtf(1.0f + 4.0f * tk * tk));
    const float ttf = (tk - 1.0f) / tnew;
    tk = tnew;

    // phase B (waves 0..10): w = y + L_inv D^T R ; shrink + momentum (M=176, N=64, K=64)
    if (wave < 11) {
      floatx4 acc[4];
      #pragma unroll
      for (int nt = 0; nt < 4; ++nt) {
        const int nr = 16 * nt + ln;
        const char* rrow = smc + BY_R + nr * RROW;
        const half8 rb0 = *(const half8*)(rrow + SWZ(nr, 16 * q));
        const half8 rb1 = *(const half8*)(rrow + SWZ(nr, 64 + 16 * q));
        floatx4 a = {0.f,0.f,0.f,0.f};
        a = MFMA16(DtH[0], rb0, a, 0, 0, 0);
        a = MFMA16(DtL[0], rb0, a, 0, 0, 0);
        a = MFMA16(DtH[1], rb1, a, 0, 0, 0);
        a = MFMA16(DtL[1], rb1, a, 0, 0, 0);
        acc[nt] = a;
      }
      const int p0 = 16 * wave + 4 * q;
      #pragma unroll
      for (int nt = 0; nt < 4; ++nt) {
        const int nr = 16 * nt + ln;
        half4 hv;
        #pragma unroll
        for (int r = 0; r < 4; ++r) {
          const float w = yR[nt][r] + L_inv * acc[nt][r];
          const float cl = fminf(fmaxf(w, -thr), thr);   // v_med3 clamp
          const float xn = w - cl;                        // softshrink
          const float yn = xn + ttf * (xn - xR[nt][r]);
          xR[nt][r] = xn;
          yR[nt][r] = yn;
          hv[r] = (half_t)yn;
        }
        *(half4*)(smc + BY_Y + nr * YROW + SWZ(nr, p0 * 2)) = hv;
      }
    }
    __syncthreads();
  }

  // ---- G. outputs: C = x_fin
  float* Cb = outC + b * PDIM * NCOL;
  if (wave < 11) {
    #pragma unroll
    for (int nt = 0; nt < 4; ++nt) {
      const int c = 16 * nt + ln;
      if (c < NCOL) {
        #pragma unroll
        for (int r = 0; r < 4; ++r) {
          const int p = 16 * wave + 4 * q + r;
          if (p < PDIM) Cb[p * NCOL + c] = xR[nt][r];
        }
      }
    }
  }
  // reconst = D @ C : restage x into Y (fp16), rerun phase-A GEMM
  if (wave < 11) {
    const int p0 = 16 * wave + 4 * q;
    #pragma unroll
    for (int nt = 0; nt < 4; ++nt) {
      const int nr = 16 * nt + ln;
      half4 hv;
      #pragma unroll
      for (int r = 0; r < 4; ++r) hv[r] = (half_t)xR[nt][r];
      *(half4*)(smc + BY_Y + nr * YROW + SWZ(nr, p0 * 2)) = hv;
    }
  }
  __syncthreads();
  {
    floatx4 aH0 = {0.f,0.f,0.f,0.f}, aH1 = {0.f,0.f,0.f,0.f};
    floatx4 aL0 = {0.f,0.f,0.f,0.f}, aL1 = {0.f,0.f,0.f,0.f};
    const int n0 = 16 * ntA + ln;
    const char* yrow = smc + BY_Y + n0 * YROW;
    #pragma unroll
    for (int ks = 0; ks < NKA; ++ks) {
      const int kb = (32 * ks + 8 * q) * 2;
      const half8 b0 = *(const half8*)(yrow + SWZ(n0, kb));
      if (ks & 1) {
        aH1 = MFMA16(DhF[ks], b0, aH1, 0, 0, 0);
        aL1 = MFMA16(DlF[ks], b0, aL1, 0, 0, 0);
      } else {
        aH0 = MFMA16(DhF[ks], b0, aH0, 0, 0, 0);
        aL0 = MFMA16(DlF[ks], b0, aL0, 0, 0, 0);
      }
    }
    float* Rb = outR + b * TDIM * NCOL;
    const int c = 16 * ntA + ln;
    if (c < NCOL) {
      const int t0 = 16 * mtA + 4 * q;
      #pragma unroll
      for (int r = 0; r < 4; ++r) {
        const int t = t0 + r;
        if (t < TDIM) Rb[t * NCOL + c] = (aH0[r] + aH1[r]) + (aL0[r] + aL1[r]);
      }
    }
  }
}

// ---------------- launch --------------------------------------------------------------

extern "C" void kernel_launch(void* const* d_in, const int* in_sizes, int n_in,
                              void* d_out, int out_size, void* d_ws, size_t ws_size,
                              hipStream_t stream) {
  const float* x     = (const float*)d_in[0];   // (256, 36, 50)
  const float* rho   = (const float*)d_in[1];   // (80,)
  const float* theta = (const float*)d_in[2];   // (80,)

  float* out    = (float*)d_out;
  float* outC   = out;                              // 256*161*50
  float* outDic = out + 256 * PDIM * NCOL;          // 36*161
  float* outR   = outDic + TDIM * PDIM;             // 256*36*50

  hipLaunchKernelGGL(dan_kernel, dim3(256), dim3(768), LDS_TOTAL, stream,
                     x, rho, theta, outC, outDic, outR);
}